// Round 31
// baseline (48.132 us; speedup 1.0000x reference)
//
#include <hip/hip_runtime.h>

#define P 7
#define NCH 256
#define NPP 49
#define CHIT 8          // channels per wave (serial, consecutive)
#define LDS_CAP 1280    // worst padded-f2 = 1128 (w'<=2, h'<=200); f4 gated exactly

typedef float f2 __attribute__((ext_vector_type(2), aligned(8)));
typedef float f4 __attribute__((ext_vector_type(4), aligned(16)));

__device__ __forceinline__ int rfl(int x) { return __builtin_amdgcn_readfirstlane(x); }

__global__ __launch_bounds__(128) void pooler_kernel(
    const float* __restrict__ boxes,
    const int* __restrict__ batch_ids,
    const float* __restrict__ g0, const float* __restrict__ g1,
    const float* __restrict__ g2, const float* __restrict__ g3,
    float* __restrict__ out)
{
    __shared__ __align__(16) float sreg[2][LDS_CAP];   // 10 KB -> 16 blocks/CU
                                                       // = 32 waves (fills both
                                                       // LDS and WG-slot limits)
    const int n    = blockIdx.y;          // box
    const int cq   = blockIdx.x;          // channel 16-group 0..15
    const int lane = threadIdx.x;         // 0..63
    const int wy   = threadIdx.y;         // wave 0..1

    // ---- box + level (wave-uniform; SGPR via rfl) ----
    const float x1i = boxes[n*4+0], y1i = boxes[n*4+1];
    const float x2i = boxes[n*4+2], y2i = boxes[n*4+3];
    const float area = (x2i - x1i) * (y2i - y1i);
    float lvlf = floorf(4.0f + log2f(sqrtf(area) / 224.0f + 1e-6f));
    lvlf = fminf(fmaxf(lvlf, 2.0f), 5.0f);
    const int lvl = rfl((int)lvlf - 2);   // 0..3

    const float* feat = (lvl==0) ? g0 : (lvl==1) ? g1 : (lvl==2) ? g2 : g3;
    const int    L    = (lvl==0) ? 200 : (lvl==1) ? 100 : (lvl==2) ? 50 : 25;
    const float scale = (lvl==0) ? 0.25f : (lvl==1) ? 0.125f
                      : (lvl==2) ? 0.0625f : 0.03125f;
    const int b  = batch_ids[n];
    const int LL = L * L;

    const float x1 = x1i * scale, y1 = y1i * scale;
    const float bw = fmaxf(x2i*scale - x1, 1.0f) * (1.0f/7.0f);
    const float bh = fmaxf(y2i*scale - y1, 1.0f) * (1.0f/7.0f);
    const float Lf = (float)L, Lm1 = Lf - 1.0f;
    const int   Lm2 = L - 2;

    // ---- region bounds -> SGPRs ----
    const int rx0 = rfl(min((int)fminf(fmaxf(x1 + 0.25f*bw, 0.0f), Lm1), Lm2));
    const int rx1 = rfl(min((int)fminf(fmaxf(x1 + 6.75f*bw, 0.0f), Lm1), Lm2));
    const int ry0 = rfl(min((int)fminf(fmaxf(y1 + 0.25f*bh, 0.0f), Lm1), Lm2));
    const int ry1 = rfl(min((int)fminf(fmaxf(y1 + 6.75f*bh, 0.0f), Lm1), Lm2));
    const int Hr  = ry1 - ry0 + 2;
    const int Hm1 = Hr - 1;

    // ---- width-class + aligned layout (all SALU) ----
    int path, rx0a, WrA, stride;
    if (lvl <= 1) {
        const int a4 = rx0 & ~3;
        const int W4 = (rx1 + 2 - a4 + 3) & ~3;
        const int s4 = ((W4 & 7) == 4) ? W4 : W4 + 4;
        if (W4 >= 16 && Hr * s4 <= LDS_CAP) {
            path = 0; rx0a = a4; WrA = W4; stride = s4;
        } else {
            path = 1; rx0a = rx0 & ~1;
            WrA = (rx1 + 2 - rx0a + 1) & ~1;
            stride = ((WrA & 3) == 2) ? WrA : WrA + 2;
        }
    } else if (lvl == 2) {
        path = 1; rx0a = rx0 & ~1;
        WrA = (rx1 + 2 - rx0a + 1) & ~1;
        stride = ((WrA & 3) == 2) ? WrA : WrA + 2;
    } else {
        path = 2; rx0a = rx0; WrA = rx1 + 2 - rx0;
        stride = WrA | 1;
    }
    if (Hr * stride > LDS_CAP) stride = WrA;   // safety net (near-never taken)

    // ---- interp prep ONCE (channel-independent) ----
    const int py = (lane < NPP) ? lane / P : 6;
    const int px = (lane < NPP) ? lane - py * P : 6;
    float wta[2][2], wtb[2][2], wtc[2][2], wtd[2][2];
    int   adr[2][2];
    {
        int   y0[2], x0[2];
        float fy[2], hy[2], vy[2], fx[2], hx[2], vx[2];
#pragma unroll
        for (int s = 0; s < 2; ++s) {
            const float yc = y1 + ((float)py + (s ? 0.75f : 0.25f)) * bh;
            vy[s] = (yc > -1.0f && yc < Lf) ? 1.0f : 0.0f;
            const float ycc = fminf(fmaxf(yc, 0.0f), Lm1);
            y0[s] = min((int)ycc, Lm2);
            fy[s] = ycc - (float)y0[s];
            hy[s] = 1.0f - fy[s];

            const float xc = x1 + ((float)px + (s ? 0.75f : 0.25f)) * bw;
            vx[s] = (xc > -1.0f && xc < Lf) ? 1.0f : 0.0f;
            const float xcc = fminf(fmaxf(xc, 0.0f), Lm1);
            x0[s] = min((int)xcc, Lm2);
            fx[s] = xcc - (float)x0[s];
            hx[s] = 1.0f - fx[s];
        }
#pragma unroll
        for (int sy = 0; sy < 2; ++sy)
#pragma unroll
        for (int sx = 0; sx < 2; ++sx) {
            const float w = 0.25f * vy[sy] * vx[sx];
            wta[sy][sx] = w * hy[sy] * hx[sx];
            wtb[sy][sx] = w * hy[sy] * fx[sx];
            wtc[sy][sx] = w * fy[sy] * hx[sx];
            wtd[sy][sx] = w * fy[sy] * fx[sx];
            adr[sy][sx] = (y0[sy] - ry0) * stride - rx0a + x0[sx];
        }
    }

    // ---- staging lane geometry ONCE (pow2 cols-per-row -> rows-per-pass) ----
    const int qpr  = WrA >> 2;
    const int p2q  = (qpr > 1) ? (32 - __clz(qpr - 1)) : 0;
    const int rp4  = 64 >> p2q;
    const int sub4 = lane >> p2q;
    const int cq4  = min((lane & ((1 << p2q) - 1)) << 2, WrA - 4);
    const int ppr  = WrA >> 1;
    const int p2p  = (ppr > 1) ? (32 - __clz(ppr - 1)) : 0;
    const int rp2  = 64 >> p2p;
    const int sub2 = lane >> p2p;
    const int cp2  = min((lane & ((1 << p2p) - 1)) << 1, WrA - 2);
    const int p2c  = (WrA > 1) ? (32 - __clz(WrA - 1)) : 0;
    const int rp1  = 64 >> p2c;
    const int sub1 = lane >> p2c;
    const int cc1  = min(lane & ((1 << p2c) - 1), WrA - 1);

    float* sp = sreg[wy];
    const int c_first = (cq * 2 + wy) * CHIT;
    size_t ob = ((size_t)n * NCH + c_first) * NPP + lane;

    for (int it = 0; it < CHIT; ++it) {
        const int poff = rfl((b * NCH + c_first + it) * LL + ry0 * L + rx0a);
        const float* gp = feat + poff;

        // ---- stage region -> LDS (2 row-groups per iter = 2 loads in flight) ----
        if (path == 0) {
            for (int r = 0; r < Hr; r += 2 * rp4) {
                const int rA = min(r + sub4, Hm1);
                const int rB = min(r + rp4 + sub4, Hm1);
                const f4 vA = *(const f4*)(gp + rA * L + cq4);
                const f4 vB = *(const f4*)(gp + rB * L + cq4);
                *(f4*)(sp + rA * stride + cq4) = vA;
                *(f4*)(sp + rB * stride + cq4) = vB;   // tail dup = same data
            }
        } else if (path == 1) {
            for (int r = 0; r < Hr; r += 2 * rp2) {
                const int rA = min(r + sub2, Hm1);
                const int rB = min(r + rp2 + sub2, Hm1);
                const f2 vA = *(const f2*)(gp + rA * L + cp2);
                const f2 vB = *(const f2*)(gp + rB * L + cp2);
                *(f2*)(sp + rA * stride + cp2) = vA;
                *(f2*)(sp + rB * stride + cp2) = vB;
            }
        } else {
            for (int r = 0; r < Hr; r += 2 * rp1) {
                const int rA = min(r + sub1, Hm1);
                const int rB = min(r + rp1 + sub1, Hm1);
                const float vA = gp[rA * L + cc1];
                const float vB = gp[rB * L + cc1];
                sp[rA * stride + cc1] = vA;
                sp[rB * stride + cc1] = vB;
            }
        }
        // NO barrier: sreg[wy] is wave-private; per-wave DS ops complete in
        // program order, so iter k's ds_reads finish before k+1's writes.

        // ---- interp from LDS (weights + addresses precomputed) ----
        if (lane < NPP) {
            float acc = 0.0f;
#pragma unroll
            for (int sy = 0; sy < 2; ++sy)
#pragma unroll
            for (int sx = 0; sx < 2; ++sx) {
                const int a = adr[sy][sx];
                acc += wta[sy][sx] * sp[a]
                     + wtb[sy][sx] * sp[a + 1]
                     + wtc[sy][sx] * sp[a + stride]
                     + wtd[sy][sx] * sp[a + stride + 1];
            }
            __builtin_nontemporal_store(acc, &out[ob]);   // out never re-read
        }
        ob += NPP;                                        // next channel
    }
}

extern "C" void kernel_launch(void* const* d_in, const int* in_sizes, int n_in,
                              void* d_out, int out_size, void* d_ws, size_t ws_size,
                              hipStream_t stream) {
    const float* boxes     = (const float*)d_in[0];
    const int*   batch_ids = (const int*)d_in[1];
    const float* g0        = (const float*)d_in[2];
    const float* g1        = (const float*)d_in[3];
    const float* g2        = (const float*)d_in[4];
    const float* g3        = (const float*)d_in[5];
    float* out = (float*)d_out;

    const int N = in_sizes[0] / 4;                 // 512
    dim3 block(64, 2);                             // 2 waves; wave = 8 channels serial
    dim3 grid(NCH / (CHIT * 2), N);                // (16, 512) = 8192 blocks
    pooler_kernel<<<grid, block, 0, stream>>>(boxes, batch_ids, g0, g1, g2, g3, out);
}